// Round 10
// baseline (80.848 us; speedup 1.0000x reference)
//
#include <hip/hip_runtime.h>

#define SS 2704                // 52*52
#define NA 5
#define NC 20
#define NB 128
#define CELLS (NB * SS)        // 346112
#define TILE 64                // cells per block
#define TPB 320                // 5 waves; wave index == anchor index
#define NBLK (CELLS / TILE)    // 5408
#define RBLOCK 1024
#define T_DWORDS (CELLS * 125)     // 43,264,000
#define T_F4 (T_DWORDS / 4)        // 10,816,000 (divides exactly)
#define MASK_BYTES ((size_t)CELLS * NA)  // 1,730,560 (16-aligned)
#define FLAG_TPB 256
#define FLAG_BLOCKS 2048

__device__ __forceinline__ float fast_sigmoid(float x) {
    return __builtin_amdgcn_rcpf(1.0f + __expf(-x));
}
__device__ __forceinline__ float fast_softplus(float x) {
    // logaddexp(0,x) = max(x,0) + log(1 + exp(-|x|)); all HW instrs
    return fmaxf(x, 0.0f) + __logf(1.0f + __expf(-fabsf(x)));
}

// Pass 1: stream T fully coalesced (float4), extract obj flags into a byte
// mask. Each flag dword is owned by exactly one thread -> plain stores, no
// atomics, every mask byte written every call (no memset, no stale state).
__global__ __launch_bounds__(FLAG_TPB) void yolo_flags(
        const float4* __restrict__ T4, unsigned char* __restrict__ mask) {
    const int stride = FLAG_TPB * FLAG_BLOCKS;
    for (int i = blockIdx.x * FLAG_TPB + threadIdx.x; i < T_F4; i += stride) {
        float4 v = T4[i];
        int g0   = i * 4;              // global dword index of v.x (< 2^26)
        int cell = g0 / 125;
        int r    = g0 - cell * 125;    // offset within record, 0..124
        float vc0 = v.x, vc1 = v.y, vc2 = v.z, vc3 = v.w;
        #pragma unroll
        for (int c = 0; c < 4; ++c) {
            float vv = (c == 0) ? vc0 : (c == 1) ? vc1 : (c == 2) ? vc2 : vc3;
            int rr = r + c;
            int cc = cell;
            if (rr >= 125) { rr -= 125; cc += 1; }
            int q = rr / 25;                       // anchor index if flag slot
            if (rr - q * 25 == 4)                  // flag slots: 4,29,54,79,104
                mask[(size_t)cc * NA + q] = (vv != 0.0f) ? 1 : 0;
        }
    }
}

// Pass 2: round-8 structure. block = 64-cell tile; wave = anchor; lane = cell.
// Flags come from the L2-resident mask (3-line coalesced read per wave)
// instead of a 64-line scatter into T. Class loss stays wave-compacted.
template <bool USE_MASK>
__global__ __launch_bounds__(TPB) void yolo_main(
        const float* __restrict__ P,      // (B, 125, S, S)
        const float* __restrict__ T,      // (B, S, S, 5, 25)
        const float* __restrict__ anch,   // (5, 2)
        const unsigned char* __restrict__ mask,
        float* __restrict__ partial) {
    __shared__ float red[NA][4];

    int a    = threadIdx.x >> 6;          // 0..4, wave-uniform
    int lane = threadIdx.x & 63;
    int base_cell = blockIdx.x * TILE;
    int cell = base_cell + lane;
    int b    = cell / SS;
    int ij   = cell - b * SS;

    const float* Ta = T + (size_t)cell * 125 + a * 25;            // record
    const float* Pa = P + ((size_t)b * 125 + a * 25) * SS + ij;   // plane base
    float aw  = anch[2 * a];
    float ahv = anch[2 * a + 1];

    bool isobj;
    if (USE_MASK)
        isobj = mask[(size_t)cell * NA + a] != 0;   // L1/L2 hit, coalesced span
    else
        isobj = (Ta[4] != 0.0f);
    float cp = fast_sigmoid(Pa[4 * SS]);            // coalesced span

    float s_xywh = 0.0f, s_cls = 0.0f, s_obj = 0.0f, s_noobj = 0.0f;

    if (isobj) {
        // ---- gated box / IoU / obj-conf part (~3 lanes) ----
        float tx = Pa[0], ty = Pa[SS], tw = Pa[2 * SS], th = Pa[3 * SS];
        float gx = Ta[0], gy = Ta[1], gw = Ta[2], gh = Ta[3];
        float cx = fast_sigmoid(tx), cy = fast_sigmoid(ty);
        float pw = __expf(tw) * aw;
        float ph = __expf(th) * ahv;
        // IoU invariant to common (+j,+i) shift -> dropped.
        float iw = fmaxf(fminf(gx + 0.5f * gw, cx + 0.5f * pw) -
                         fmaxf(gx - 0.5f * gw, cx - 0.5f * pw), 0.0f);
        float ih = fmaxf(fminf(gy + 0.5f * gh, cy + 0.5f * ph) -
                         fmaxf(gy - 0.5f * gh, cy - 0.5f * ph), 0.0f);
        float inter = iw * ih;
        float uni   = gw * gh + pw * ph - inter;
        float iou   = (uni > 0.0f) ? inter * __builtin_amdgcn_rcpf(uni) : 0.0f;

        float dx = cx - gx, dy = cy - gy;
        s_xywh += dx * dx + dy * dy;
        const float eps = 1e-6f;
        float dw = __fsqrt_rn(pw + eps) - __fsqrt_rn(gw + eps);
        float dh = __fsqrt_rn(ph + eps) - __fsqrt_rn(gh + eps);
        s_xywh += dw * dw + dh * dh;

        float dob = iou - cp;
        s_obj += dob * dob;
    } else {
        s_noobj = cp * cp;
    }

    // ---- wave-compacted class loss ----
    unsigned long long act = __ballot(isobj);     // wave-uniform
    int nact = __popcll(act);
    int slot_off = lane / 20;                     // 0,1,2 (lanes 60-63 idle)
    int c = lane - slot_off * 20;                 // class index 0..19
    unsigned long long m = act;
    for (int basep = 0; basep < nact; basep += 3) {
        unsigned long long m0 = m;
        unsigned long long m1 = m0 & (m0 - 1);
        unsigned long long m2 = m1 & (m1 - 1);
        int src0 = __ffsll(m0) - 1;
        int src1 = __ffsll(m1) - 1;
        int src2 = __ffsll(m2) - 1;
        m = m2 & (m2 - 1);

        int s   = basep + slot_off;
        int src = (slot_off == 0) ? src0 : (slot_off == 1) ? src1 : src2;
        if (slot_off < 3 && s < nact) {
            int pcell = base_cell + src;
            int pb    = pcell / SS;
            int pij   = pcell - pb * SS;
            float tt = T[(size_t)pcell * 125 + a * 25 + 5 + c];
            float l  = P[((size_t)pb * 125 + a * 25 + 5 + c) * SS + pij];
            s_cls += fast_softplus(l) - l * tt;
        }
    }

    // ---- wave reduce (64 lanes), then cross-wave via tiny LDS ----
    #pragma unroll
    for (int off = 32; off > 0; off >>= 1) {
        s_xywh  += __shfl_xor(s_xywh,  off, 64);
        s_cls   += __shfl_xor(s_cls,   off, 64);
        s_obj   += __shfl_xor(s_obj,   off, 64);
        s_noobj += __shfl_xor(s_noobj, off, 64);
    }
    if (lane == 0) {
        red[a][0] = s_xywh; red[a][1] = s_cls; red[a][2] = s_obj; red[a][3] = s_noobj;
    }
    __syncthreads();
    if (threadIdx.x == 0) {
        float r0 = 0, r1 = 0, r2 = 0, r3 = 0;
        #pragma unroll
        for (int w = 0; w < NA; ++w) {
            r0 += red[w][0]; r1 += red[w][1]; r2 += red[w][2]; r3 += red[w][3];
        }
        float* p = partial + (size_t)blockIdx.x * 4;
        p[0] = r0; p[1] = r1; p[2] = r2; p[3] = r3;
    }
}

__global__ __launch_bounds__(RBLOCK) void yolo_reduce(
        const float* __restrict__ partial, int n, float* __restrict__ out) {
    float v0 = 0.0f, v1 = 0.0f, v2 = 0.0f, v3 = 0.0f;
    for (int i = threadIdx.x; i < n; i += RBLOCK) {
        const float* p = partial + (size_t)i * 4;
        v0 += p[0]; v1 += p[1]; v2 += p[2]; v3 += p[3];
    }
    #pragma unroll
    for (int off = 32; off > 0; off >>= 1) {
        v0 += __shfl_xor(v0, off, 64);
        v1 += __shfl_xor(v1, off, 64);
        v2 += __shfl_xor(v2, off, 64);
        v3 += __shfl_xor(v3, off, 64);
    }
    __shared__ float red[RBLOCK / 64][4];
    int wid = threadIdx.x >> 6, lane = threadIdx.x & 63;
    if (lane == 0) {
        red[wid][0] = v0; red[wid][1] = v1; red[wid][2] = v2; red[wid][3] = v3;
    }
    __syncthreads();
    if (threadIdx.x == 0) {
        float xywh = 0, cls = 0, obj = 0, noobj = 0;
        #pragma unroll
        for (int q = 0; q < RBLOCK / 64; ++q) {
            xywh += red[q][0]; cls += red[q][1]; obj += red[q][2]; noobj += red[q][3];
        }
        out[0] = 5.0f * xywh + 5.0f * obj + 0.5f * noobj + cls;
        out[1] = xywh;
        out[2] = cls;
        out[3] = obj + noobj;
    }
}

extern "C" void kernel_launch(void* const* d_in, const int* in_sizes, int n_in,
                              void* d_out, int out_size, void* d_ws, size_t ws_size,
                              hipStream_t stream) {
    const float* P = (const float*)d_in[0];
    const float* T = (const float*)d_in[1];
    const float* anch = (const float*)d_in[2];
    float* out = (float*)d_out;

    size_t need = MASK_BYTES + (size_t)NBLK * 4 * sizeof(float);
    if (ws_size >= need) {
        unsigned char* mask = (unsigned char*)d_ws;
        float* partial = (float*)((char*)d_ws + MASK_BYTES);
        yolo_flags<<<FLAG_BLOCKS, FLAG_TPB, 0, stream>>>((const float4*)T, mask);
        yolo_main<true><<<NBLK, TPB, 0, stream>>>(P, T, anch, mask, partial);
        yolo_reduce<<<1, RBLOCK, 0, stream>>>(partial, NBLK, out);
    } else {
        float* partial = (float*)d_ws;  // 86.5 KB fallback (round-8 path)
        yolo_main<false><<<NBLK, TPB, 0, stream>>>(P, T, anch, nullptr, partial);
        yolo_reduce<<<1, RBLOCK, 0, stream>>>(partial, NBLK, out);
    }
}

// Round 11
// 63.798 us; speedup vs baseline: 1.2673x; 1.2673x over previous
//
#include <hip/hip_runtime.h>

#define SS 2704                // 52*52
#define NA 5
#define NC 20
#define NB 128
#define CELLS (NB * SS)        // 346112
#define TILE 64                // cells per block
#define TPB 320                // 5 waves; wave index == anchor index
#define NBLK (CELLS / TILE)    // 5408
#define NPART (NBLK * NA)      // 27040 float4 partials
#define RBLOCK 1024

__device__ __forceinline__ float fast_sigmoid(float x) {
    return __builtin_amdgcn_rcpf(1.0f + __expf(-x));
}
__device__ __forceinline__ float fast_softplus(float x) {
    // logaddexp(0,x) = max(x,0) + log(1 + exp(-|x|)); all HW instrs
    return fmaxf(x, 0.0f) + __logf(1.0f + __expf(-fabsf(x)));
}

// block = 64-cell tile; wave = anchor; lane = cell-in-tile. No LDS, no
// barriers at all: each wave shfl-reduces and lane 0 writes one float4
// partial. Class loss wave-compacted via ballot (3 pairs x 20 classes
// spread over 60 lanes per pass).
__global__ __launch_bounds__(TPB) void yolo_main(
        const float* __restrict__ P,      // (B, 125, S, S)
        const float* __restrict__ T,      // (B, S, S, 5, 25)
        const float* __restrict__ anch,   // (5, 2)
        float4* __restrict__ partial) {
    int a    = threadIdx.x >> 6;          // 0..4, wave-uniform
    int lane = threadIdx.x & 63;
    int base_cell = blockIdx.x * TILE;
    int cell = base_cell + lane;
    int b    = cell / SS;
    int ij   = cell - b * SS;

    const float* Ta = T + (size_t)cell * 125 + a * 25;            // record
    const float* Pa = P + ((size_t)b * 125 + a * 25) * SS + ij;   // plane base
    float aw  = anch[2 * a];
    float ahv = anch[2 * a + 1];

    float fl = Ta[4];
    float cp = fast_sigmoid(Pa[4 * SS]);          // coalesced span

    float s_xywh = 0.0f, s_cls = 0.0f, s_obj = 0.0f, s_noobj = 0.0f;
    bool isobj = (fl != 0.0f);

    if (isobj) {
        // ---- gated box / IoU / obj-conf part (~3 lanes) ----
        float tx = Pa[0], ty = Pa[SS], tw = Pa[2 * SS], th = Pa[3 * SS];
        float gx = Ta[0], gy = Ta[1], gw = Ta[2], gh = Ta[3];
        float cx = fast_sigmoid(tx), cy = fast_sigmoid(ty);
        float pw = __expf(tw) * aw;
        float ph = __expf(th) * ahv;
        // IoU invariant to common (+j,+i) shift -> dropped.
        float iw = fmaxf(fminf(gx + 0.5f * gw, cx + 0.5f * pw) -
                         fmaxf(gx - 0.5f * gw, cx - 0.5f * pw), 0.0f);
        float ih = fmaxf(fminf(gy + 0.5f * gh, cy + 0.5f * ph) -
                         fmaxf(gy - 0.5f * gh, cy - 0.5f * ph), 0.0f);
        float inter = iw * ih;
        float uni   = gw * gh + pw * ph - inter;
        float iou   = (uni > 0.0f) ? inter * __builtin_amdgcn_rcpf(uni) : 0.0f;

        float dx = cx - gx, dy = cy - gy;
        s_xywh += dx * dx + dy * dy;
        const float eps = 1e-6f;
        float dw = __fsqrt_rn(pw + eps) - __fsqrt_rn(gw + eps);
        float dh = __fsqrt_rn(ph + eps) - __fsqrt_rn(gh + eps);
        s_xywh += dw * dw + dh * dh;

        float dob = iou - cp;
        s_obj += dob * dob;
    } else {
        s_noobj = cp * cp;
    }

    // ---- wave-compacted class loss ----
    unsigned long long act = __ballot(isobj);     // wave-uniform
    int nact = __popcll(act);
    int slot_off = lane / 20;                     // 0,1,2 (lanes 60-63 idle)
    int c = lane - slot_off * 20;                 // class index 0..19
    const float* Tcls = T + (size_t)a * 25 + 5 + c;       // + cell*125
    const float* Pcls = P + ((size_t)(a * 25 + 5 + c)) * SS;  // + b*125*SS + ij
    unsigned long long m = act;
    for (int basep = 0; basep < nact; basep += 3) {
        unsigned long long m0 = m;
        unsigned long long m1 = m0 & (m0 - 1);
        unsigned long long m2 = m1 & (m1 - 1);
        int src0 = __ffsll(m0) - 1;
        int src1 = __ffsll(m1) - 1;
        int src2 = __ffsll(m2) - 1;
        m = m2 & (m2 - 1);

        int s   = basep + slot_off;
        int src = (slot_off == 0) ? src0 : (slot_off == 1) ? src1 : src2;
        if (slot_off < 3 && s < nact) {
            int pcell = base_cell + src;
            int pb    = pcell / SS;
            int pij   = pcell - pb * SS;
            float tt = Tcls[(size_t)pcell * 125];
            float l  = Pcls[(size_t)pb * 125 * SS + pij];
            s_cls += fast_softplus(l) - l * tt;
        }
    }

    // ---- wave reduce (64 lanes); lane 0 writes this wave's partial ----
    #pragma unroll
    for (int off = 32; off > 0; off >>= 1) {
        s_xywh  += __shfl_xor(s_xywh,  off, 64);
        s_cls   += __shfl_xor(s_cls,   off, 64);
        s_obj   += __shfl_xor(s_obj,   off, 64);
        s_noobj += __shfl_xor(s_noobj, off, 64);
    }
    if (lane == 0)
        partial[blockIdx.x * NA + a] = make_float4(s_xywh, s_cls, s_obj, s_noobj);
}

__global__ __launch_bounds__(RBLOCK) void yolo_reduce(
        const float4* __restrict__ partial, int n, float* __restrict__ out) {
    float v0 = 0.0f, v1 = 0.0f, v2 = 0.0f, v3 = 0.0f;
    for (int i = threadIdx.x; i < n; i += RBLOCK) {
        float4 p = partial[i];
        v0 += p.x; v1 += p.y; v2 += p.z; v3 += p.w;
    }
    #pragma unroll
    for (int off = 32; off > 0; off >>= 1) {
        v0 += __shfl_xor(v0, off, 64);
        v1 += __shfl_xor(v1, off, 64);
        v2 += __shfl_xor(v2, off, 64);
        v3 += __shfl_xor(v3, off, 64);
    }
    __shared__ float red[RBLOCK / 64][4];
    int wid = threadIdx.x >> 6, lane = threadIdx.x & 63;
    if (lane == 0) {
        red[wid][0] = v0; red[wid][1] = v1; red[wid][2] = v2; red[wid][3] = v3;
    }
    __syncthreads();
    if (threadIdx.x == 0) {
        float xywh = 0, cls = 0, obj = 0, noobj = 0;
        #pragma unroll
        for (int q = 0; q < RBLOCK / 64; ++q) {
            xywh += red[q][0]; cls += red[q][1]; obj += red[q][2]; noobj += red[q][3];
        }
        out[0] = 5.0f * xywh + 5.0f * obj + 0.5f * noobj + cls;
        out[1] = xywh;
        out[2] = cls;
        out[3] = obj + noobj;
    }
}

extern "C" void kernel_launch(void* const* d_in, const int* in_sizes, int n_in,
                              void* d_out, int out_size, void* d_ws, size_t ws_size,
                              hipStream_t stream) {
    const float* P = (const float*)d_in[0];
    const float* T = (const float*)d_in[1];
    const float* anch = (const float*)d_in[2];
    float* out = (float*)d_out;
    float4* partial = (float4*)d_ws;   // NPART * 16 B = 432.6 KB

    yolo_main<<<NBLK, TPB, 0, stream>>>(P, T, anch, partial);
    yolo_reduce<<<1, RBLOCK, 0, stream>>>(partial, NPART, out);
}

// Round 12
// 57.176 us; speedup vs baseline: 1.4140x; 1.1158x over previous
//
#include <hip/hip_runtime.h>

#define SS 2704                // 52*52
#define NA 5
#define NC 20
#define NB 128
#define CELLS (NB * SS)        // 346112
#define TILE 64                // cells per block
#define TPB 320                // 5 waves; wave index == anchor index
#define NBLK (CELLS / TILE)    // 5408
#define RBLOCK 1024

__device__ __forceinline__ float fast_sigmoid(float x) {
    return __builtin_amdgcn_rcpf(1.0f + __expf(-x));
}
__device__ __forceinline__ float fast_softplus(float x) {
    // logaddexp(0,x) = max(x,0) + log(1 + exp(-|x|)); all HW instrs
    return fmaxf(x, 0.0f) + __logf(1.0f + __expf(-fabsf(x)));
}

// block = 64-cell tile; wave = anchor; lane = cell-in-tile. No LDS staging
// (L1 serves the block's shared 32KB T-window). Class loss is wave-compacted:
// ballot the ~3 obj lanes, then spread 3 pairs x 20 class elems over 60 lanes
// per pass -- softplus runs once per pass instead of 20x at 5% lane duty.
// Measured best structure: 57.4 us (r8). All structural alternatives measured
// worse: LDS staging r4, reg-pipeline r5 (spill), global_load_lds dbuf r6
// (barrier drain), 4-tile ILP r9 (L1 window break), 2-pass mask r10 (re-pays
// T stream), barrierless tail r11 (reduce tail 5x).
__global__ __launch_bounds__(TPB) void yolo_main(
        const float* __restrict__ P,      // (B, 125, S, S)
        const float* __restrict__ T,      // (B, S, S, 5, 25)
        const float* __restrict__ anch,   // (5, 2)
        float* __restrict__ partial) {
    __shared__ float red[NA][4];

    int a    = threadIdx.x >> 6;          // 0..4, wave-uniform
    int lane = threadIdx.x & 63;
    int base_cell = blockIdx.x * TILE;
    int cell = base_cell + lane;
    int b    = cell / SS;
    int ij   = cell - b * SS;

    const float* Ta = T + (size_t)cell * 125 + a * 25;            // record
    const float* Pa = P + ((size_t)b * 125 + a * 25) * SS + ij;   // plane base
    float aw  = anch[2 * a];
    float ahv = anch[2 * a + 1];

    float fl = Ta[4];
    float cp = fast_sigmoid(Pa[4 * SS]);          // coalesced span

    float s_xywh = 0.0f, s_cls = 0.0f, s_obj = 0.0f, s_noobj = 0.0f;
    bool isobj = (fl != 0.0f);

    if (isobj) {
        // ---- gated box / IoU / obj-conf part (~3 lanes) ----
        float tx = Pa[0], ty = Pa[SS], tw = Pa[2 * SS], th = Pa[3 * SS];
        float gx = Ta[0], gy = Ta[1], gw = Ta[2], gh = Ta[3];
        float cx = fast_sigmoid(tx), cy = fast_sigmoid(ty);
        float pw = __expf(tw) * aw;
        float ph = __expf(th) * ahv;
        // IoU invariant to common (+j,+i) shift -> dropped.
        float iw = fmaxf(fminf(gx + 0.5f * gw, cx + 0.5f * pw) -
                         fmaxf(gx - 0.5f * gw, cx - 0.5f * pw), 0.0f);
        float ih = fmaxf(fminf(gy + 0.5f * gh, cy + 0.5f * ph) -
                         fmaxf(gy - 0.5f * gh, cy - 0.5f * ph), 0.0f);
        float inter = iw * ih;
        float uni   = gw * gh + pw * ph - inter;
        float iou   = (uni > 0.0f) ? inter * __builtin_amdgcn_rcpf(uni) : 0.0f;

        float dx = cx - gx, dy = cy - gy;
        s_xywh += dx * dx + dy * dy;
        const float eps = 1e-6f;
        float dw = __fsqrt_rn(pw + eps) - __fsqrt_rn(gw + eps);
        float dh = __fsqrt_rn(ph + eps) - __fsqrt_rn(gh + eps);
        s_xywh += dw * dw + dh * dh;

        float dob = iou - cp;
        s_obj += dob * dob;
    } else {
        s_noobj = cp * cp;
    }

    // ---- wave-compacted class loss ----
    unsigned long long act = __ballot(isobj);     // wave-uniform
    int nact = __popcll(act);
    int slot_off = lane / 20;                     // 0,1,2 (lanes 60-63 idle)
    int c = lane - slot_off * 20;                 // class index 0..19
    unsigned long long m = act;
    for (int basep = 0; basep < nact; basep += 3) {
        unsigned long long m0 = m;
        unsigned long long m1 = m0 & (m0 - 1);
        unsigned long long m2 = m1 & (m1 - 1);
        int src0 = __ffsll(m0) - 1;
        int src1 = __ffsll(m1) - 1;
        int src2 = __ffsll(m2) - 1;
        m = m2 & (m2 - 1);

        int s   = basep + slot_off;
        int src = (slot_off == 0) ? src0 : (slot_off == 1) ? src1 : src2;
        if (slot_off < 3 && s < nact) {
            int pcell = base_cell + src;
            int pb    = pcell / SS;
            int pij   = pcell - pb * SS;
            float tt = T[(size_t)pcell * 125 + a * 25 + 5 + c];
            float l  = P[((size_t)pb * 125 + a * 25 + 5 + c) * SS + pij];
            s_cls += fast_softplus(l) - l * tt;
        }
    }

    // ---- wave reduce (64 lanes), then cross-wave via tiny LDS ----
    #pragma unroll
    for (int off = 32; off > 0; off >>= 1) {
        s_xywh  += __shfl_xor(s_xywh,  off, 64);
        s_cls   += __shfl_xor(s_cls,   off, 64);
        s_obj   += __shfl_xor(s_obj,   off, 64);
        s_noobj += __shfl_xor(s_noobj, off, 64);
    }
    if (lane == 0) {
        red[a][0] = s_xywh; red[a][1] = s_cls; red[a][2] = s_obj; red[a][3] = s_noobj;
    }
    __syncthreads();
    if (threadIdx.x == 0) {
        float r0 = 0, r1 = 0, r2 = 0, r3 = 0;
        #pragma unroll
        for (int w = 0; w < NA; ++w) {
            r0 += red[w][0]; r1 += red[w][1]; r2 += red[w][2]; r3 += red[w][3];
        }
        float* p = partial + (size_t)blockIdx.x * 4;
        p[0] = r0; p[1] = r1; p[2] = r2; p[3] = r3;
    }
}

__global__ __launch_bounds__(RBLOCK) void yolo_reduce(
        const float* __restrict__ partial, int n, float* __restrict__ out) {
    float v0 = 0.0f, v1 = 0.0f, v2 = 0.0f, v3 = 0.0f;
    for (int i = threadIdx.x; i < n; i += RBLOCK) {
        const float* p = partial + (size_t)i * 4;
        v0 += p[0]; v1 += p[1]; v2 += p[2]; v3 += p[3];
    }
    #pragma unroll
    for (int off = 32; off > 0; off >>= 1) {
        v0 += __shfl_xor(v0, off, 64);
        v1 += __shfl_xor(v1, off, 64);
        v2 += __shfl_xor(v2, off, 64);
        v3 += __shfl_xor(v3, off, 64);
    }
    __shared__ float red[RBLOCK / 64][4];
    int wid = threadIdx.x >> 6, lane = threadIdx.x & 63;
    if (lane == 0) {
        red[wid][0] = v0; red[wid][1] = v1; red[wid][2] = v2; red[wid][3] = v3;
    }
    __syncthreads();
    if (threadIdx.x == 0) {
        float xywh = 0, cls = 0, obj = 0, noobj = 0;
        #pragma unroll
        for (int q = 0; q < RBLOCK / 64; ++q) {
            xywh += red[q][0]; cls += red[q][1]; obj += red[q][2]; noobj += red[q][3];
        }
        out[0] = 5.0f * xywh + 5.0f * obj + 0.5f * noobj + cls;
        out[1] = xywh;
        out[2] = cls;
        out[3] = obj + noobj;
    }
}

extern "C" void kernel_launch(void* const* d_in, const int* in_sizes, int n_in,
                              void* d_out, int out_size, void* d_ws, size_t ws_size,
                              hipStream_t stream) {
    const float* P = (const float*)d_in[0];
    const float* T = (const float*)d_in[1];
    const float* anch = (const float*)d_in[2];
    float* out = (float*)d_out;
    float* partial = (float*)d_ws;   // NBLK * 4 floats = 86.5 KB

    yolo_main<<<NBLK, TPB, 0, stream>>>(P, T, anch, partial);
    yolo_reduce<<<1, RBLOCK, 0, stream>>>(partial, NBLK, out);
}